// Round 6
// baseline (443.634 us; speedup 1.0000x reference)
//
#include <hip/hip_runtime.h>
#include <hip/hip_bf16.h>
#include <cstdint>
#include <cstddef>

#define S_LEN 2048
#define BATCHN 2
#define DMODEL 1024
#define NHEADS 16
#define DHEAD 64
#define DFF 4096
#define NTOK (S_LEN*BATCHN)   // 4096 tokens
#define MB (1u<<20)

typedef __bf16 bf16x8 __attribute__((ext_vector_type(8)));
typedef __bf16 bf16x4 __attribute__((ext_vector_type(4)));
typedef float f32x4 __attribute__((ext_vector_type(4)));
typedef __hip_bfloat16 bf16s;

// Q pre-scale: 1/sqrt(64) * log2(e)  (softmax runs in exp2 domain)
#define QSCALE 0.18033688011112042592f

__device__ static inline void gload_lds16(const void* g, void* l) {
  __builtin_amdgcn_global_load_lds((const __attribute__((address_space(1))) void*)g,
                                   (__attribute__((address_space(3))) void*)l,
                                   16, 0, 0);
}

// ---------------- pack kernels ----------------

__global__ __launch_bounds__(256) void transpose_convert4(const float* __restrict__ s0,
                                                          const float* __restrict__ s1,
                                                          const float* __restrict__ s2,
                                                          const float* __restrict__ s3,
                                                          bf16s* __restrict__ dst) {
  __shared__ float tile[32][33];
  const float* in = (blockIdx.z == 0) ? s0 : (blockIdx.z == 1) ? s1 : (blockIdx.z == 2) ? s2 : s3;
  bf16s* out = dst + (size_t)blockIdx.z * DMODEL * DMODEL;
  const int tx = threadIdx.x & 31;
  const int ty = threadIdx.x >> 5;
  const int bx = blockIdx.x * 32;
  const int by = blockIdx.y * 32;
#pragma unroll
  for (int i = 0; i < 32; i += 8)
    tile[ty + i][tx] = in[(size_t)(by + ty + i) * DMODEL + bx + tx];
  __syncthreads();
#pragma unroll
  for (int i = 0; i < 32; i += 8)
    out[(size_t)(bx + ty + i) * DMODEL + by + tx] = __float2bfloat16(tile[tx][ty + i]);
}

__global__ __launch_bounds__(256) void transpose_convert(const float* __restrict__ in,
                                                         bf16s* __restrict__ out,
                                                         int K, int N) {
  __shared__ float tile[32][33];
  const int tx = threadIdx.x & 31;
  const int ty = threadIdx.x >> 5;
  const int bx = blockIdx.x * 32;
  const int by = blockIdx.y * 32;
#pragma unroll
  for (int i = 0; i < 32; i += 8)
    tile[ty + i][tx] = in[(size_t)(by + ty + i) * N + bx + tx];
  __syncthreads();
#pragma unroll
  for (int i = 0; i < 32; i += 8)
    out[(size_t)(bx + ty + i) * K + by + tx] = __float2bfloat16(tile[tx][ty + i]);
}

__global__ __launch_bounds__(256) void cvt_bf16_kernel(const float* __restrict__ in,
                                                       bf16s* __restrict__ out, int n4) {
  int i = blockIdx.x * 256 + threadIdx.x;
  if (i < n4) {
    float4 v = ((const float4*)in)[i];
    union { bf16s h[4]; uint2 u; } pk;
    pk.h[0] = __float2bfloat16(v.x); pk.h[1] = __float2bfloat16(v.y);
    pk.h[2] = __float2bfloat16(v.z); pk.h[3] = __float2bfloat16(v.w);
    ((uint2*)out)[i] = pk.u;
  }
}

__global__ __launch_bounds__(256) void bias_concat_kernel(const float* __restrict__ bq,
                                                          const float* __restrict__ bk,
                                                          const float* __restrict__ bv,
                                                          float* __restrict__ bqkv) {
  int i = blockIdx.x * 256 + threadIdx.x;
  if (i < 3 * DMODEL) {
    float v = (i < DMODEL) ? bq[i] : (i < 2 * DMODEL ? bk[i - DMODEL] : bv[i - 2 * DMODEL]);
    bqkv[i] = v;
  }
}

// ---------------- GEMM: 256x256 8-phase counted-vmcnt pipeline ----------------
// 8 waves (2M x 4N), per-wave out 128x64, acc[8][4]. BK=64 as two K=32 halves.
// LDS: 4 rotating slabs x 32KB (A-half 16KB | B-half 16KB) = 128KB.
// Per phase: stage 1 half-tile (2 gload_lds, 3 K-halves ahead), 4-8 ds_read_b128,
// barrier, lgkmcnt(0), setprio(1), 16 MFMA, setprio(0), barrier.
// vmcnt(4) once per K-half (vmcnt(0) before last). Slab write-safety: stage for
// K-half n+4 issues after the end-barrier of K-half n's last phase (same slab).
// T2 swizzle: off ^= ((off>>6)&3)<<4 (both-sides-consistent, rule #21).
// EPI: 0 = QKV scatter (+bias, Q*QSCALE)  1 = f32 partial (splitK via bz)
//      2 = bf16 out (+bias, exact GELU)
template<int EPI>
__global__ __launch_bounds__(512, 2)
void gemm8p_kernel(const bf16s* __restrict__ A, const bf16s* __restrict__ Bt,
                   int N, int K, int kchunk, int gx, int plane,
                   const float* __restrict__ bias,
                   float* __restrict__ outF, bf16s* __restrict__ outB,
                   bf16s* __restrict__ Qb, bf16s* __restrict__ Kb, bf16s* __restrict__ Vtb)
{
  __shared__ __align__(1024) char lds[131072];
  const int tid = threadIdx.x;
  const int l = tid & 63, w = tid >> 6;
  const int lr = l & 15, lg = l >> 4;
  const int wr = w >> 2, wc = w & 3;

  // XCD-chunked bijective block swizzle (gridDim.x % 8 == 0 for all launches)
  const int nb = gridDim.x;
  const int lin = blockIdx.x;
  const int sw = (lin & 7) * (nb >> 3) + (lin >> 3);
  const int bz = sw / plane;
  const int tpl = sw - bz * plane;
  const int by = tpl / gx, bx = tpl - by * gx;
  const int m0 = by * 256, n0 = bx * 256, kbeg = bz * kchunk;
  const int NKH = kchunk >> 5;          // K=32 halves in this chunk

  const char* Ab = (const char*)A + ((size_t)m0 * K + kbeg) * 2;
  const char* Bb = (const char*)Bt + ((size_t)n0 * K + kbeg) * 2;
  const size_t Krow = (size_t)K * 2;

  f32x4 acc[8][4] = {};

  // stage half-tile h: K-half n = h>>1, matrix = h&1 (0=A rows, 1=B rows).
  // Linear LDS dest (gload_lds requirement) + inverse-swizzled global source.
  auto stageH = [&](int h) {
    if (h >= 2 * NKH) return;
    const int n = h >> 1;
    char* dst = lds + (n & 3) * 32768 + (h & 1) * 16384;
    const char* src = (h & 1) ? Bb : Ab;
#pragma unroll
    for (int c = 0; c < 2; ++c) {
      int L = c * 8192 + tid * 16;
      int U = L ^ (((L >> 6) & 3) << 4);
      gload_lds16(src + (size_t)(U >> 6) * Krow + (size_t)n * 64 + (U & 63), dst + L);
    }
  };

  const int swzc = (lr & 3) << 4;
  const int kcol = (lg * 16) ^ swzc;            // swizzled K-byte within 64B row
  const int aoff = (wr * 128 + lr) * 64;        // + mi*1024
  const int boff = 16384 + (wc * 64 + lr) * 64; // + ni*1024

  // prologue: stage K-halves 0,1,2 (6 half-tiles = 12 loads); wait first K-half
#pragma unroll
  for (int h = 0; h < 6; ++h) stageH(h);
  asm volatile("s_waitcnt vmcnt(8)" ::: "memory");
  __builtin_amdgcn_s_barrier();

  for (int n = 0; n < NKH; ++n) {
    const char* slab = lds + (n & 3) * 32768;
    // ---- phase 2n: mi 0-3 x ni 0-3 ----
    stageH(2 * n + 6);
    bf16x8 bf[4], af[4];
#pragma unroll
    for (int ni = 0; ni < 4; ++ni) bf[ni] = *(const bf16x8*)(slab + boff + ni * 1024 + kcol);
#pragma unroll
    for (int mi = 0; mi < 4; ++mi) af[mi] = *(const bf16x8*)(slab + aoff + mi * 1024 + kcol);
    __builtin_amdgcn_s_barrier();
    asm volatile("s_waitcnt lgkmcnt(0)" ::: "memory");
    __builtin_amdgcn_sched_barrier(0);
    __builtin_amdgcn_s_setprio(1);
#pragma unroll
    for (int mi = 0; mi < 4; ++mi)
#pragma unroll
      for (int ni = 0; ni < 4; ++ni)
        acc[mi][ni] = __builtin_amdgcn_mfma_f32_16x16x32_bf16(af[mi], bf[ni], acc[mi][ni], 0, 0, 0);
    __builtin_amdgcn_s_setprio(0);
    __builtin_amdgcn_s_barrier();
    // ---- phase 2n+1: mi 4-7 x ni 0-3 (B-frags kept in regs) ----
    stageH(2 * n + 7);
#pragma unroll
    for (int mi = 0; mi < 4; ++mi) af[mi] = *(const bf16x8*)(slab + aoff + 4096 + mi * 1024 + kcol);
    if (n + 1 < NKH) {
      if (n + 1 == NKH - 1) asm volatile("s_waitcnt vmcnt(0)" ::: "memory");
      else                  asm volatile("s_waitcnt vmcnt(4)" ::: "memory");
    }
    __builtin_amdgcn_s_barrier();
    asm volatile("s_waitcnt lgkmcnt(0)" ::: "memory");
    __builtin_amdgcn_sched_barrier(0);
    __builtin_amdgcn_s_setprio(1);
#pragma unroll
    for (int mi = 0; mi < 4; ++mi)
#pragma unroll
      for (int ni = 0; ni < 4; ++ni)
        acc[4 + mi][ni] = __builtin_amdgcn_mfma_f32_16x16x32_bf16(af[mi], bf[ni], acc[4 + mi][ni], 0, 0, 0);
    __builtin_amdgcn_s_setprio(0);
    __builtin_amdgcn_s_barrier();
  }

  // epilogue
  float* outFz = outF + (size_t)bz * ((size_t)NTOK * DMODEL);
#pragma unroll
  for (int mi = 0; mi < 8; ++mi) {
#pragma unroll
    for (int ni = 0; ni < 4; ++ni) {
#pragma unroll
      for (int r = 0; r < 4; ++r) {
        int row = m0 + wr * 128 + mi * 16 + lg * 4 + r;
        int col = n0 + wc * 64 + ni * 16 + lr;
        float v = acc[mi][ni][r];
        if (EPI == 0) {
          v += bias[col];
          int which = col >> 10;
          int h = (col & 1023) >> 6;
          int d = col & 63;
          int b = row & 1;
          int s = row >> 1;
          if (which == 0)
            Qb[(((size_t)(b * NHEADS + h)) * S_LEN + s) * DHEAD + d] = __float2bfloat16(v * QSCALE);
          else if (which == 1)
            Kb[(((size_t)(b * NHEADS + h)) * S_LEN + s) * DHEAD + d] = __float2bfloat16(v);
          else
            Vtb[(((size_t)(b * NHEADS + h)) * DHEAD + d) * S_LEN + s] = __float2bfloat16(v);
        } else if (EPI == 1) {
          outFz[(size_t)row * N + col] = v;
        } else {
          v += bias[col];
          float gv = 0.5f * v * (1.0f + erff(v * 0.70710678118654752f));
          outB[(size_t)row * N + col] = __float2bfloat16(gv);
        }
      }
    }
  }
}

// ---------------- flash attention (round-2 proven: 4 waves x 32 q-rows) ----------------
__global__ __launch_bounds__(256, 2)
void attn_kernel(const bf16s* __restrict__ Qb, const bf16s* __restrict__ Kb,
                 const bf16s* __restrict__ Vtb, bf16s* __restrict__ ctx)
{
  __shared__ __align__(1024) char lds[51200];
  const int tid = threadIdx.x;
  const int l = tid & 63, w = tid >> 6;
  const int lr = l & 15, lg = l >> 4;

  int lin = blockIdx.x;
  int wg = (lin & 7) * 64 + (lin >> 3);
  int qb = wg & 15;
  int hb = wg >> 4;
  int h = hb & 15, b = hb >> 4;

  const char* Qg = (const char*)(Qb + ((size_t)(b * NHEADS + h)) * S_LEN * DHEAD);
  const char* Kg = (const char*)(Kb + ((size_t)(b * NHEADS + h)) * S_LEN * DHEAD);
  const char* Vg = (const char*)(Vtb + ((size_t)(b * NHEADS + h)) * DHEAD * S_LEN);

  const int swz = (lr & 7) << 4;
  const int aK0 = lr * 128 + ((lg * 16) ^ swz);
  const int aK1 = lr * 128 + ((64 + lg * 16) ^ swz);
  const int klane = (l >> 3) * 128  + (((l & 7) * 16) ^ ((l & 56) << 1));
  const int vlane = (l >> 3) * 4096 + (((l & 7) * 16) ^ ((l & 56) << 1));
  const int l16 = l * 16;
  char* Pw = lds + 32768 + w * 4608;
  const int pwA = lr * 144 + lg * 8;
  const int prA = lr * 144 + lg * 16;

  const int q0 = qb * 128 + w * 32;
  bf16x8 aq[2][2];
#pragma unroll
  for (int qi = 0; qi < 2; ++qi)
#pragma unroll
    for (int kk = 0; kk < 2; ++kk)
      aq[qi][kk] = *(const bf16x8*)(Qg + (size_t)(q0 + qi * 16 + lr) * 128 + kk * 64 + lg * 16);

  f32x4 o0[4] = {}, o1[4] = {};
  float m0 = -1e30f, m1 = -1e30f;
  float ls0 = 0.f, ls1 = 0.f;

  const int NT = S_LEN / 64;

  auto stage = [&](char* dK, int tile) {
    const char* kbg = Kg + (size_t)tile * 8192;
    const char* vbg = Vg + (size_t)tile * 128;
    char* dV = dK + 8192;
#pragma unroll
    for (int i = 0; i < 2; ++i) {
      int c = w * 2 + i;
      gload_lds16(kbg + c * 1024 + klane, dK + c * 1024 + l16);
      gload_lds16(vbg + (size_t)c * 32768 + vlane, dV + c * 1024 + l16);
    }
  };

  stage(lds, 0);
  asm volatile("s_waitcnt vmcnt(0)" ::: "memory");
  __builtin_amdgcn_s_barrier();

#define ATTN_ITER(BUF, t)                                                        \
  {                                                                              \
    int nxt = ((t) + 1 < NT) ? (t) + 1 : NT - 1;                                 \
    stage(lds + ((BUF) ^ 1) * 16384, nxt);                                       \
    const char* bK = lds + (BUF) * 16384;                                        \
    const char* bV = bK + 8192;                                                  \
    f32x4 st0[4], st1[4];                                                        \
    _Pragma("unroll")                                                            \
    for (int ni = 0; ni < 4; ++ni) {                                             \
      bf16x8 k0 = *(const bf16x8*)(bK + ni * 2048 + aK0);                        \
      bf16x8 k1 = *(const bf16x8*)(bK + ni * 2048 + aK1);                        \
      f32x4 z = {};                                                              \
      st0[ni] = __builtin_amdgcn_mfma_f32_16x16x32_bf16(k0, aq[0][0], z, 0, 0, 0);\
      st0[ni] = __builtin_amdgcn_mfma_f32_16x16x32_bf16(k1, aq[0][1], st0[ni], 0, 0, 0);\
      st1[ni] = __builtin_amdgcn_mfma_f32_16x16x32_bf16(k0, aq[1][0], z, 0, 0, 0);\
      st1[ni] = __builtin_amdgcn_mfma_f32_16x16x32_bf16(k1, aq[1][1], st1[ni], 0, 0, 0);\
    }                                                                            \
    f32x4 vm0 = st0[0], vm1 = st1[0];                                            \
    _Pragma("unroll")                                                            \
    for (int ni = 1; ni < 4; ++ni) {                                             \
      _Pragma("unroll")                                                          \
      for (int r = 0; r < 4; ++r) {                                              \
        vm0[r] = fmaxf(vm0[r], st0[ni][r]);                                      \
        vm1[r] = fmaxf(vm1[r], st1[ni][r]);                                      \
      }                                                                          \
    }                                                                            \
    float mx0 = fmaxf(fmaxf(vm0[0], vm0[1]), fmaxf(vm0[2], vm0[3]));             \
    float mx1 = fmaxf(fmaxf(vm1[0], vm1[1]), fmaxf(vm1[2], vm1[3]));             \
    mx0 = fmaxf(mx0, __shfl_xor(mx0, 16)); mx0 = fmaxf(mx0, __shfl_xor(mx0, 32));\
    mx1 = fmaxf(mx1, __shfl_xor(mx1, 16)); mx1 = fmaxf(mx1, __shfl_xor(mx1, 32));\
    if (!__all(mx0 <= m0 + 8.f && mx1 <= m1 + 8.f)) {                            \
      float nm0 = fmaxf(m0, mx0), nm1 = fmaxf(m1, mx1);                          \
      float al0 = exp2f(m0 - nm0), al1 = exp2f(m1 - nm1);                        \
      m0 = nm0; m1 = nm1; ls0 *= al0; ls1 *= al1;                                \
      _Pragma("unroll")                                                          \
      for (int r = 0; r < 4; ++r) {                                              \
        float s0r = __shfl(al0, lg * 4 + r);                                     \
        float s1r = __shfl(al1, lg * 4 + r);                                     \
        _Pragma("unroll")                                                        \
        for (int di = 0; di < 4; ++di) { o0[di][r] *= s0r; o1[di][r] *= s1r; }   \
      }                                                                          \
    }                                                                            \
    f32x4 ac0 = {}, ac1 = {};                                                    \
    _Pragma("unroll")                                                            \
    for (int ni = 0; ni < 4; ++ni) {                                             \
      _Pragma("unroll")                                                          \
      for (int r = 0; r < 4; ++r) {                                              \
        st0[ni][r] = exp2f(st0[ni][r] - m0);                                     \
        st1[ni][r] = exp2f(st1[ni][r] - m1);                                     \
      }                                                                          \
      ac0 += st0[ni]; ac1 += st1[ni];                                            \
    }                                                                            \
    ls0 += ac0[0] + ac0[1] + ac0[2] + ac0[3];                                    \
    ls1 += ac1[0] + ac1[1] + ac1[2] + ac1[3];                                    \
    _Pragma("unroll")                                                            \
    for (int ni = 0; ni < 4; ++ni) {                                             \
      bf16x4 p0, p1;                                                             \
      _Pragma("unroll")                                                          \
      for (int j = 0; j < 4; ++j) { p0[j] = (__bf16)st0[ni][j]; p1[j] = (__bf16)st1[ni][j]; }\
      *(bf16x4*)(Pw + pwA + ni * 32) = p0;                                       \
      *(bf16x4*)(Pw + 2304 + pwA + ni * 32) = p1;                                \
    }                                                                            \
    _Pragma("unroll")                                                            \
    for (int kk = 0; kk < 2; ++kk) {                                             \
      bf16x8 ap0 = *(const bf16x8*)(Pw + prA + kk * 64);                         \
      bf16x8 ap1 = *(const bf16x8*)(Pw + 2304 + prA + kk * 64);                  \
      const int av = kk ? aK1 : aK0;                                             \
      _Pragma("unroll")                                                          \
      for (int di = 0; di < 4; ++di) {                                           \
        bf16x8 vv = *(const bf16x8*)(bV + di * 2048 + av);                       \
        o0[di] = __builtin_amdgcn_mfma_f32_16x16x32_bf16(ap0, vv, o0[di], 0, 0, 0);\
        o1[di] = __builtin_amdgcn_mfma_f32_16x16x32_bf16(ap1, vv, o1[di], 0, 0, 0);\
      }                                                                          \
    }                                                                            \
    asm volatile("s_waitcnt vmcnt(0)" ::: "memory");                             \
    __builtin_amdgcn_s_barrier();                                                \
  }

  for (int t = 0; t < NT; t += 2) {
    ATTN_ITER(0, t);
    ATTN_ITER(1, t + 1);
  }
#undef ATTN_ITER

#pragma unroll
  for (int qi = 0; qi < 2; ++qi) {
    float ls = qi ? ls1 : ls0;
    ls += __shfl_xor(ls, 16);
    ls += __shfl_xor(ls, 32);
    float inv = 1.0f / ls;
#pragma unroll
    for (int r = 0; r < 4; ++r) {
      float invr = __shfl(inv, lg * 4 + r);
      int srow = q0 + qi * 16 + lg * 4 + r;
      int tkn = srow * BATCHN + b;
#pragma unroll
      for (int di = 0; di < 4; ++di) {
        int d = h * DHEAD + di * 16 + lr;
        float v = (qi ? o1[di][r] : o0[di][r]) * invr;
        ctx[(size_t)tkn * DMODEL + d] = __float2bfloat16(v);
      }
    }
  }
}

// ---------------- layernorm over (inA + inB + resid + bias) ----------------
template<int WB>
__global__ __launch_bounds__(256)
void ln_kernel(const float* __restrict__ inA, const float* __restrict__ inB,
               const float* __restrict__ resid, const float* __restrict__ bias,
               const float* __restrict__ g, const float* __restrict__ be,
               float* __restrict__ outF, bf16s* __restrict__ outB)
{
  const int row = blockIdx.x;
  const int tid = threadIdx.x;
  const size_t base = (size_t)row * DMODEL;
  float4 a = ((const float4*)(inA + base))[tid];
  float4 bq = ((const float4*)(inB + base))[tid];
  float4 rr = ((const float4*)(resid + base))[tid];
  float4 bi = ((const float4*)bias)[tid];
  float4 v;
  v.x = a.x + bq.x + rr.x + bi.x;
  v.y = a.y + bq.y + rr.y + bi.y;
  v.z = a.z + bq.z + rr.z + bi.z;
  v.w = a.w + bq.w + rr.w + bi.w;
  float s = v.x + v.y + v.z + v.w;
  float s2 = v.x * v.x + v.y * v.y + v.z * v.z + v.w * v.w;
#pragma unroll
  for (int m = 1; m < 64; m <<= 1) { s += __shfl_xor(s, m); s2 += __shfl_xor(s2, m); }
  __shared__ float sm[8];
  const int wv = tid >> 6, l = tid & 63;
  if (l == 0) { sm[wv] = s; sm[4 + wv] = s2; }
  __syncthreads();
  s = sm[0] + sm[1] + sm[2] + sm[3];
  s2 = sm[4] + sm[5] + sm[6] + sm[7];
  float mean = s * (1.0f / DMODEL);
  float var = s2 * (1.0f / DMODEL) - mean * mean;
  float rstd = rsqrtf(var + 1e-5f);
  float4 gv = ((const float4*)g)[tid];
  float4 bv = ((const float4*)be)[tid];
  float o0 = (v.x - mean) * rstd * gv.x + bv.x;
  float o1 = (v.y - mean) * rstd * gv.y + bv.y;
  float o2 = (v.z - mean) * rstd * gv.z + bv.z;
  float o3 = (v.w - mean) * rstd * gv.w + bv.w;
  float4 ov = {o0, o1, o2, o3};
  ((float4*)(outF + base))[tid] = ov;
  if (WB) {
    union { bf16s h[4]; uint2 u; } pk;
    pk.h[0] = __float2bfloat16(o0); pk.h[1] = __float2bfloat16(o1);
    pk.h[2] = __float2bfloat16(o2); pk.h[3] = __float2bfloat16(o3);
    ((uint2*)(outB + base))[tid] = pk.u;
  }
}

// ---------------- launch ----------------
extern "C" void kernel_launch(void* const* d_in, const int* in_sizes, int n_in,
                              void* d_out, int out_size, void* d_ws, size_t ws_size,
                              hipStream_t stream) {
  const float* x  = (const float*)d_in[0];
  const float* Wq = (const float*)d_in[1];
  const float* bq = (const float*)d_in[2];
  const float* Wk = (const float*)d_in[3];
  const float* bk = (const float*)d_in[4];
  const float* Wv = (const float*)d_in[5];
  const float* bv = (const float*)d_in[6];
  const float* Wo = (const float*)d_in[7];
  const float* bo = (const float*)d_in[8];
  const float* W1 = (const float*)d_in[9];
  const float* b1 = (const float*)d_in[10];
  const float* W2 = (const float*)d_in[11];
  const float* b2 = (const float*)d_in[12];
  const float* g1 = (const float*)d_in[13];
  const float* be1 = (const float*)d_in[14];
  const float* g2 = (const float*)d_in[15];
  const float* be2 = (const float*)d_in[16];

  // explicit workspace layout (113 MB total; aliasing documented per region)
  char* ws = (char*)d_ws;
  if (ws_size < (size_t)113 * MB) return;
  bf16s* Wqkv_t = (bf16s*)(ws + (size_t)0 * MB);    // [0,6)
  bf16s* Wo_t   = (bf16s*)(ws + (size_t)6 * MB);    // [6,8)
  bf16s* W1_t   = (bf16s*)(ws + (size_t)8 * MB);    // [8,16)
  bf16s* W2_t   = (bf16s*)(ws + (size_t)16 * MB);   // [16,24)
  float* bqkv   = (float*)(ws + (size_t)24 * MB);   // [24,25)
  bf16s* Xb     = (bf16s*)(ws + (size_t)25 * MB);   // [25,33)  dead after QKV
  bf16s* y1     = (bf16s*)(ws + (size_t)25 * MB);   //   aliases Xb (written by LN1)
  bf16s* Qb     = (bf16s*)(ws + (size_t)33 * MB);   // [33,41)  dead after attn
  bf16s* Kb     = (bf16s*)(ws + (size_t)41 * MB);   // [41,49)  dead after attn
  bf16s* Vtb    = (bf16s*)(ws + (size_t)49 * MB);   // [49,57)  dead after attn
  bf16s* ctx    = (bf16s*)(ws + (size_t)57 * MB);   // [57,65)  dead after Wo
  bf16s* Hb     = (bf16s*)(ws + (size_t)33 * MB);   //   32MB, aliases Qb..ctx (dead)
  float* p01    = (float*)(ws + (size_t)65 * MB);   // [65,97)  splitK partials x2
  float* y1f    = (float*)(ws + (size_t)97 * MB);   // [97,113)
  float* p0 = p01;
  float* p1 = p01 + (size_t)NTOK * DMODEL;

  transpose_convert4<<<dim3(32, 32, 4), 256, 0, stream>>>(Wq, Wk, Wv, Wo, Wqkv_t);
  transpose_convert<<<dim3(DFF / 32, DMODEL / 32), 256, 0, stream>>>(W1, W1_t, DMODEL, DFF);
  transpose_convert<<<dim3(DMODEL / 32, DFF / 32), 256, 0, stream>>>(W2, W2_t, DFF, DMODEL);
  bias_concat_kernel<<<12, 256, 0, stream>>>(bq, bk, bv, bqkv);
  cvt_bf16_kernel<<<(NTOK * DMODEL / 4 + 255) / 256, 256, 0, stream>>>(x, Xb, NTOK * DMODEL / 4);

  // QKV projection: 16x12 tiles = 192 blocks
  gemm8p_kernel<0><<<192, 512, 0, stream>>>(
      Xb, Wqkv_t, 3 * DMODEL, DMODEL, DMODEL, 12, 192, bqkv,
      nullptr, nullptr, Qb, Kb, Vtb);

  attn_kernel<<<512, 256, 0, stream>>>(Qb, Kb, Vtb, ctx);

  // Wo projection: 16x4 tiles, splitK x2 (kchunk 512) = 128 blocks -> p0,p1
  gemm8p_kernel<1><<<128, 512, 0, stream>>>(
      ctx, Wo_t, DMODEL, DMODEL, DMODEL / 2, 4, 64, nullptr,
      p01, nullptr, nullptr, nullptr, nullptr);
  // LN1: (p0 + p1 + x + bo) -> y1 (bf16) + y1f (f32)
  ln_kernel<1><<<NTOK, 256, 0, stream>>>(p0, p1, x, bo, g1, be1, y1f, y1);
  // FF1 + GELU -> Hb: 16x16 tiles = 256 blocks
  gemm8p_kernel<2><<<256, 512, 0, stream>>>(
      y1, W1_t, DFF, DMODEL, DMODEL, 16, 256, b1,
      nullptr, Hb, nullptr, nullptr, nullptr);
  // FF2: 16x4 tiles, splitK x2 (kchunk 2048) = 128 blocks -> p0,p1
  gemm8p_kernel<1><<<128, 512, 0, stream>>>(
      Hb, W2_t, DMODEL, DFF, DFF / 2, 4, 64, nullptr,
      p01, nullptr, nullptr, nullptr, nullptr);
  // LN2: (p0 + p1 + y1f + b2) -> d_out (f32)
  ln_kernel<0><<<NTOK, 256, 0, stream>>>(p0, p1, y1f, b2, g2, be2, (float*)d_out, nullptr);
}